// Round 8
// baseline (545.497 us; speedup 1.0000x reference)
//
#include <hip/hip_runtime.h>
#include <hip/hip_bf16.h>
#include <cstddef>

#define D_MODEL 384
#define D_INNER 768
#define D_STATE 16
#define DT_RANK 24
#define K_CONV  4
#define BATCH   8
#define SEQ     2048
#define BL      (BATCH * SEQ)     // 16384 rows
#define NCHUNK  64
#define LCHUNK  (SEQ / NCHUNK)    // 32
#define XDBL_LD 64                // padded leading dim of x_dbl buffer
#define LOG2E   1.44269504088896f

typedef unsigned short ushort_t;
typedef __bf16 bf16x8 __attribute__((ext_vector_type(8)));
typedef float  f32x4  __attribute__((ext_vector_type(4)));
typedef unsigned short u16x8 __attribute__((ext_vector_type(8)));

#define GLOBAL_AS(p) ((const __attribute__((address_space(1))) void*)(p))
#define LDS_AS(p)    ((__attribute__((address_space(3))) void*)(p))

__device__ __forceinline__ ushort_t f32_to_bf16_rne(float v) {
    unsigned int u = __float_as_uint(v);
    return (ushort_t)((u + 0x7FFFu + ((u >> 16) & 1u)) >> 16);
}
__device__ __forceinline__ float bf16_to_f32(ushort_t u) {
    return __uint_as_float(((unsigned int)u) << 16);
}

// Build w^1..w^16 with a depth-4 product tree (breaks the serial pw chain).
__device__ __forceinline__ void pow_tree16(float w1, float* pw) {
    float w2 = w1 * w1, w4 = w2 * w2, w8 = w4 * w4;
    pw[0] = w1;        pw[1] = w2;        pw[2] = w2 * w1;   pw[3] = w4;
    pw[4] = w4 * w1;   pw[5] = w4 * w2;   pw[6] = w4 * pw[2]; pw[7] = w8;
    pw[8] = w8 * w1;   pw[9] = w8 * w2;   pw[10] = w8 * pw[2]; pw[11] = w8 * w4;
    pw[12] = w8 * pw[4]; pw[13] = w8 * pw[5]; pw[14] = w8 * pw[6]; pw[15] = w8 * w8;
}

// ---------------------------------------------------------------------------
// Merged one-shot weight prep (casts + transposes), both directions.
// ---------------------------------------------------------------------------
#define N_INP  (2 * 1536 * D_MODEL)        // 1179648
#define N_OUTP (2 * D_MODEL * D_INNER)     // 589824
#define N_XP   (2 * 64 * D_INNER)          // 98304
#define N_CW   (2 * K_CONV * D_INNER)      // 6144
#define N_AL   (2 * D_STATE * D_INNER)     // 24576
#define N_DW   (2 * DT_RANK * D_INNER)     // 36864
#define N_PREP (N_INP + N_OUTP + N_XP + N_CW + N_AL + N_DW)

__global__ __launch_bounds__(256) void prep_kernel(
    const float* __restrict__ in_proj, const float* __restrict__ out_proj,
    const float* __restrict__ x_proj, const float* __restrict__ conv_w,
    const float* __restrict__ A_log, const float* __restrict__ dt_w,
    ushort_t* __restrict__ wbf_in, ushort_t* __restrict__ wbf_out,
    ushort_t* __restrict__ xp_bf, float* __restrict__ cwt,
    float* __restrict__ alt, float* __restrict__ dwt)
{
    int i = blockIdx.x * 256 + threadIdx.x;
    if (i < N_INP) {
        wbf_in[i] = f32_to_bf16_rne(in_proj[i]);
        return;
    }
    i -= N_INP;
    if (i < N_OUTP) {
        wbf_out[i] = f32_to_bf16_rne(out_proj[i]);
        return;
    }
    i -= N_OUTP;
    if (i < N_XP) {
        int c   = i % D_INNER;
        int r   = (i / D_INNER) % 64;
        int dir = i / (64 * D_INNER);
        xp_bf[i] = (r < 56)
            ? f32_to_bf16_rne(x_proj[((size_t)dir * 56 + r) * D_INNER + c])
            : (ushort_t)0;
        return;
    }
    i -= N_XP;
    if (i < N_CW) {
        int c = i % D_INNER, k = (i / D_INNER) % K_CONV, dir = i / (K_CONV * D_INNER);
        cwt[i] = conv_w[((size_t)dir * D_INNER + c) * K_CONV + k];
        return;
    }
    i -= N_CW;
    if (i < N_AL) {
        int d = i % D_INNER, n = (i / D_INNER) % D_STATE, dir = i / (D_STATE * D_INNER);
        alt[i] = A_log[((size_t)dir * D_INNER + d) * D_STATE + n];
        return;
    }
    i -= N_AL;
    if (i < N_DW) {
        int d = i % D_INNER, r = (i / D_INNER) % DT_RANK, dir = i / (DT_RANK * D_INNER);
        dwt[i] = dt_w[((size_t)dir * D_INNER + d) * DT_RANK + r];
    }
}

// ---------------------------------------------------------------------------
// Detect the structured-A fast path: exp(A_log[d][n]) == n+1 (per direction).
// ---------------------------------------------------------------------------
__global__ __launch_bounds__(256) void check_A_kernel(
    const float* __restrict__ A_log, int* __restrict__ flags)
{
    __shared__ int ok[2];
    int tid = threadIdx.x;
    if (tid < 2) ok[tid] = 1;
    __syncthreads();
    for (int dir = 0; dir < 2; dir++) {
        bool good = true;
        for (int j = tid; j < D_INNER * D_STATE; j += 256) {
            int n = j % D_STATE;
            float v = __expf(A_log[(size_t)dir * D_INNER * D_STATE + j]);
            good = good && (fabsf(v - (float)(n + 1)) <= 1e-4f * (float)(n + 1));
        }
        if (!good) atomicAnd(&ok[dir], 0);
    }
    __syncthreads();
    if (tid < 2) flags[tid] = ok[tid];
}

// ---------------------------------------------------------------------------
// LayerNorm over last dim (384), output bf16. One block per row, 384 thr.
// ---------------------------------------------------------------------------
__global__ __launch_bounds__(384) void ln_kernel(
    const float* __restrict__ in, const float* __restrict__ w,
    const float* __restrict__ b, ushort_t* __restrict__ out)
{
    int row = blockIdx.x;
    int tid = threadIdx.x;
    float v = in[(size_t)row * D_MODEL + tid];
    float s = v, sq = v * v;
    #pragma unroll
    for (int o = 32; o; o >>= 1) {
        s  += __shfl_down(s, o);
        sq += __shfl_down(sq, o);
    }
    __shared__ float ss[6], ssq[6];
    __shared__ float mb[2];
    int wid = tid >> 6;
    if ((tid & 63) == 0) { ss[wid] = s; ssq[wid] = sq; }
    __syncthreads();
    if (tid == 0) {
        float S = 0.f, Q = 0.f;
        #pragma unroll
        for (int k = 0; k < 6; k++) { S += ss[k]; Q += ssq[k]; }
        float mu  = S * (1.0f / D_MODEL);
        float var = Q * (1.0f / D_MODEL) - mu * mu;
        mb[0] = mu;
        mb[1] = rsqrtf(var + 1e-5f);
    }
    __syncthreads();
    float r = (v - mb[0]) * mb[1] * w[tid] + b[tid];
    out[(size_t)row * D_MODEL + tid] = f32_to_bf16_rne(r);
}

// ---------------------------------------------------------------------------
// bf16 MFMA GEMM, bf16 output. 128x128 tile, BK=32, XOR-swizzled LDS.
// ---------------------------------------------------------------------------
__global__ __launch_bounds__(256) void gemm_mfma_b16(
    const ushort_t* __restrict__ A, const ushort_t* __restrict__ W,
    ushort_t* __restrict__ C, int N, int K)
{
    __shared__ __bf16 As[128 * 32];
    __shared__ __bf16 Ws[128 * 32];
    int tid  = threadIdx.x;
    int bm = blockIdx.x, bn = blockIdx.y;
    int lane = tid & 63, wave = tid >> 6;
    int wr = wave >> 1, wc = wave & 1;
    int quad = lane >> 4, l16 = lane & 15;
    int ca = ((quad ^ ((l16 >> 1) & 3))) * 8;          // read col (swizzled)
    int cbg = ((tid & 3) ^ ((tid >> 3) & 3)) * 8;      // staging col (swizzled)

    const ushort_t* Ag = A + (size_t)(bm * 128 + (tid >> 2)) * K + cbg;
    const ushort_t* Wg = W + (size_t)(bn * 128 + (tid >> 2)) * K + cbg;

    f32x4 acc[4][4] = {};

    for (int k0 = 0; k0 < K; k0 += 32) {
        __syncthreads();
        __builtin_amdgcn_global_load_lds(GLOBAL_AS(Ag + k0),
                                         LDS_AS(As + tid * 8), 16, 0, 0);
        __builtin_amdgcn_global_load_lds(GLOBAL_AS(Ag + (size_t)64 * K + k0),
                                         LDS_AS(As + 2048 + tid * 8), 16, 0, 0);
        __builtin_amdgcn_global_load_lds(GLOBAL_AS(Wg + k0),
                                         LDS_AS(Ws + tid * 8), 16, 0, 0);
        __builtin_amdgcn_global_load_lds(GLOBAL_AS(Wg + (size_t)64 * K + k0),
                                         LDS_AS(Ws + 2048 + tid * 8), 16, 0, 0);
        __syncthreads();

        bf16x8 af[4], wf[4];
        #pragma unroll
        for (int i = 0; i < 4; i++)
            af[i] = *(const bf16x8*)(As + (wr * 64 + i * 16 + l16) * 32 + ca);
        #pragma unroll
        for (int j = 0; j < 4; j++)
            wf[j] = *(const bf16x8*)(Ws + (wc * 64 + j * 16 + l16) * 32 + ca);
        #pragma unroll
        for (int i = 0; i < 4; i++)
            #pragma unroll
            for (int j = 0; j < 4; j++)
                acc[i][j] = __builtin_amdgcn_mfma_f32_16x16x32_bf16(
                    af[i], wf[j], acc[i][j], 0, 0, 0);
    }

    #pragma unroll
    for (int i = 0; i < 4; i++) {
        #pragma unroll
        for (int r = 0; r < 4; r++) {
            int row = bm * 128 + wr * 64 + i * 16 + quad * 4 + r;
            #pragma unroll
            for (int j = 0; j < 4; j++) {
                int col = bn * 128 + wc * 64 + j * 16 + l16;
                C[(size_t)row * N + col] = f32_to_bf16_rne(acc[i][j][r]);
            }
        }
    }
}

// ---------------------------------------------------------------------------
// bf16 MFMA GEMM, f32 output + f32 residual (out_proj). BK=32, swizzled.
// ---------------------------------------------------------------------------
__global__ __launch_bounds__(256) void gemm_mfma_f32(
    const ushort_t* __restrict__ A, const ushort_t* __restrict__ W,
    const float* __restrict__ resid, float* __restrict__ C, int N, int K)
{
    __shared__ __bf16 As[128 * 32];
    __shared__ __bf16 Ws[128 * 32];
    int tid  = threadIdx.x;
    int bm = blockIdx.x, bn = blockIdx.y;
    int lane = tid & 63, wave = tid >> 6;
    int wr = wave >> 1, wc = wave & 1;
    int quad = lane >> 4, l16 = lane & 15;
    int ca = ((quad ^ ((l16 >> 1) & 3))) * 8;
    int cbg = ((tid & 3) ^ ((tid >> 3) & 3)) * 8;

    const ushort_t* Ag = A + (size_t)(bm * 128 + (tid >> 2)) * K + cbg;
    const ushort_t* Wg = W + (size_t)(bn * 128 + (tid >> 2)) * K + cbg;

    f32x4 acc[4][4] = {};

    for (int k0 = 0; k0 < K; k0 += 32) {
        __syncthreads();
        __builtin_amdgcn_global_load_lds(GLOBAL_AS(Ag + k0),
                                         LDS_AS(As + tid * 8), 16, 0, 0);
        __builtin_amdgcn_global_load_lds(GLOBAL_AS(Ag + (size_t)64 * K + k0),
                                         LDS_AS(As + 2048 + tid * 8), 16, 0, 0);
        __builtin_amdgcn_global_load_lds(GLOBAL_AS(Wg + k0),
                                         LDS_AS(Ws + tid * 8), 16, 0, 0);
        __builtin_amdgcn_global_load_lds(GLOBAL_AS(Wg + (size_t)64 * K + k0),
                                         LDS_AS(Ws + 2048 + tid * 8), 16, 0, 0);
        __syncthreads();

        bf16x8 af[4], wf[4];
        #pragma unroll
        for (int i = 0; i < 4; i++)
            af[i] = *(const bf16x8*)(As + (wr * 64 + i * 16 + l16) * 32 + ca);
        #pragma unroll
        for (int j = 0; j < 4; j++)
            wf[j] = *(const bf16x8*)(Ws + (wc * 64 + j * 16 + l16) * 32 + ca);
        #pragma unroll
        for (int i = 0; i < 4; i++)
            #pragma unroll
            for (int j = 0; j < 4; j++)
                acc[i][j] = __builtin_amdgcn_mfma_f32_16x16x32_bf16(
                    af[i], wf[j], acc[i][j], 0, 0, 0);
    }

    #pragma unroll
    for (int i = 0; i < 4; i++) {
        #pragma unroll
        for (int r = 0; r < 4; r++) {
            int row = bm * 128 + wr * 64 + i * 16 + quad * 4 + r;
            #pragma unroll
            for (int j = 0; j < 4; j++) {
                int col = bn * 128 + wc * 64 + j * 16 + l16;
                size_t idx = (size_t)row * N + col;
                C[idx] = acc[i][j][r] + resid[idx];
            }
        }
    }
}

// ---------------------------------------------------------------------------
// x_dbl = xs(bf16) @ x_proj^T(bf16, 64x768 zero-padded), f32 out (BLx64).
// BK=32, swizzled LDS like the big GEMMs.
// ---------------------------------------------------------------------------
__global__ __launch_bounds__(256) void xdbl_mfma(
    const ushort_t* __restrict__ A, const ushort_t* __restrict__ W,
    float* __restrict__ C)
{
    __shared__ __bf16 As[128 * 32];
    __shared__ __bf16 Ws[64 * 32];
    int tid  = threadIdx.x;
    int bm = blockIdx.x;
    int lane = tid & 63, wave = tid >> 6;
    int quad = lane >> 4, l16 = lane & 15;
    int ca = ((quad ^ ((l16 >> 1) & 3))) * 8;
    int cbg = ((tid & 3) ^ ((tid >> 3) & 3)) * 8;

    const ushort_t* Ag = A + (size_t)(bm * 128 + (tid >> 2)) * D_INNER + cbg;
    const ushort_t* Wg = W + (size_t)(tid >> 2) * D_INNER + cbg;

    f32x4 acc[2][4] = {};

    for (int k0 = 0; k0 < D_INNER; k0 += 32) {
        __syncthreads();
        __builtin_amdgcn_global_load_lds(GLOBAL_AS(Ag + k0),
                                         LDS_AS(As + tid * 8), 16, 0, 0);
        __builtin_amdgcn_global_load_lds(GLOBAL_AS(Ag + (size_t)64 * D_INNER + k0),
                                         LDS_AS(As + 2048 + tid * 8), 16, 0, 0);
        __builtin_amdgcn_global_load_lds(GLOBAL_AS(Wg + k0),
                                         LDS_AS(Ws + tid * 8), 16, 0, 0);
        __syncthreads();

        bf16x8 af[2], wf[4];
        #pragma unroll
        for (int i = 0; i < 2; i++)
            af[i] = *(const bf16x8*)(As + (wave * 32 + i * 16 + l16) * 32 + ca);
        #pragma unroll
        for (int j = 0; j < 4; j++)
            wf[j] = *(const bf16x8*)(Ws + (j * 16 + l16) * 32 + ca);
        #pragma unroll
        for (int i = 0; i < 2; i++)
            #pragma unroll
            for (int j = 0; j < 4; j++)
                acc[i][j] = __builtin_amdgcn_mfma_f32_16x16x32_bf16(
                    af[i], wf[j], acc[i][j], 0, 0, 0);
    }

    #pragma unroll
    for (int i = 0; i < 2; i++) {
        #pragma unroll
        for (int r = 0; r < 4; r++) {
            int row = bm * 128 + wave * 32 + i * 16 + quad * 4 + r;
            #pragma unroll
            for (int j = 0; j < 4; j++) {
                int col = j * 16 + l16;
                C[(size_t)row * XDBL_LD + col] = acc[i][j][r];
            }
        }
    }
}

// ---------------------------------------------------------------------------
// dt = softplus(xdbl[:,0:24] @ dwt + bias), bf16 out, ROW-MAJOR [row][d].
// 64 rows per block; scalar stores are coalesced across the 768 d lanes.
// ---------------------------------------------------------------------------
__global__ __launch_bounds__(256) void dt_kernel(
    const float* __restrict__ xdbl, const float* __restrict__ dwt,
    const float* __restrict__ dtbias, ushort_t* __restrict__ dtb)
{
    int g    = blockIdx.x % 3;
    int row0 = (blockIdx.x / 3) * 64;
    int tid  = threadIdx.x;
    int d    = g * 256 + tid;
    float w[DT_RANK];
    #pragma unroll
    for (int r = 0; r < DT_RANK; r++) w[r] = dwt[r * D_INNER + d];
    float bias = dtbias[d];
    __shared__ float xd[64][DT_RANK];
    for (int idx = tid; idx < 64 * DT_RANK; idx += 256) {
        int rr = idx / DT_RANK, cc = idx % DT_RANK;
        xd[rr][cc] = xdbl[(size_t)(row0 + rr) * XDBL_LD + cc];
    }
    __syncthreads();
    #pragma unroll 4
    for (int i = 0; i < 64; i++) {
        float acc = bias;
        #pragma unroll
        for (int r = 0; r < DT_RANK; r++) acc = fmaf(xd[i][r], w[r], acc);
        float sp = acc > 20.f ? acc : __logf(1.f + __expf(acc));
        dtb[(size_t)(row0 + i) * D_INNER + d] = f32_to_bf16_rne(sp);
    }
}

// ---------------------------------------------------------------------------
// Causal depthwise conv (k=4) + bias + SiLU, bf16 in/out, 8 ch per thread.
// ---------------------------------------------------------------------------
__global__ __launch_bounds__(256) void conv_silu_kernel(
    const ushort_t* __restrict__ xz, const float* __restrict__ cwt,
    const float* __restrict__ cb, ushort_t* __restrict__ xsc, int dir)
{
    int idx8 = blockIdx.x * 256 + threadIdx.x;   // BL * 96
    int c8   = (idx8 % 96) * 8;
    int row  = idx8 / 96;
    int l    = row % SEQ;
    int b0   = row - l;

    float acc[8];
    float4 bv0 = *(const float4*)(cb + c8);
    float4 bv1 = *(const float4*)(cb + c8 + 4);
    acc[0] = bv0.x; acc[1] = bv0.y; acc[2] = bv0.z; acc[3] = bv0.w;
    acc[4] = bv1.x; acc[5] = bv1.y; acc[6] = bv1.z; acc[7] = bv1.w;

    #pragma unroll
    for (int k = 0; k < 4; k++) {
        int ls = dir ? (l + k) : (l - 3 + k);
        int wk = dir ? (3 - k) : k;
        bool ok = dir ? (ls < SEQ) : (ls >= 0);
        if (ok) {
            u16x8 v = *(const u16x8*)(xz + (size_t)(b0 + ls) * 1536 + c8);
            float4 w0 = *(const float4*)(cwt + wk * D_INNER + c8);
            float4 w1 = *(const float4*)(cwt + wk * D_INNER + c8 + 4);
            float wv[8] = {w0.x, w0.y, w0.z, w0.w, w1.x, w1.y, w1.z, w1.w};
            #pragma unroll
            for (int j = 0; j < 8; j++)
                acc[j] = fmaf(bf16_to_f32(v[j]), wv[j], acc[j]);
        }
    }
    u16x8 o;
    #pragma unroll
    for (int j = 0; j < 8; j++) {
        float sg = 1.0f / (1.0f + __expf(-acc[j]));
        o[j] = f32_to_bf16_rne(acc[j] * sg);
    }
    *(u16x8*)(xsc + (size_t)row * D_INNER + c8) = o;
}

// h-update helper for the structured-A slow path (volatile alt read defeats
// LICM so the never-taken branch can't inflate the fast path's VGPR count).
#define SLOW_H(idx, bq) { \
    float a_ = *(const volatile float*)(alt + (idx) * D_INNER + d); \
    float e_ = __builtin_amdgcn_exp2f(dtv * (-__expf(a_) * LOG2E)); \
    h[idx] = fmaf(e_, h[idx], dtx * (bq)); }

// Fast-path step bodies. Raw bf16 slot values are converted at CONSUME time
// so the prefetched loads' s_waitcnt lands 4 steps after issue.
#define P1_BODY(IROW, DRAW, XRAW) { \
    float dtv = bf16_to_f32(DRAW); \
    float xv  = bf16_to_f32(XRAW); \
    float dtx = dtv * xv; \
    sdt += dtv; \
    float pw[D_STATE]; \
    pow_tree16(__builtin_amdgcn_exp2f(-dtv * LOG2E), pw); \
    _Pragma("unroll") \
    for (int q = 0; q < 4; q++) { \
        float4 Bq = *(const float4*)&sBC[IROW][4 * q]; \
        h[4*q+0] = fmaf(pw[4*q+0], h[4*q+0], dtx * Bq.x); \
        h[4*q+1] = fmaf(pw[4*q+1], h[4*q+1], dtx * Bq.y); \
        h[4*q+2] = fmaf(pw[4*q+2], h[4*q+2], dtx * Bq.z); \
        h[4*q+3] = fmaf(pw[4*q+3], h[4*q+3], dtx * Bq.w); \
    } }

#define P3_BODY(IROW, DRAW, XRAW, ZRAW, YOFF) { \
    float dtv = bf16_to_f32(DRAW); \
    float xv  = bf16_to_f32(XRAW); \
    float zv  = bf16_to_f32(ZRAW); \
    float dtx = dtv * xv; \
    float pw[D_STATE]; \
    pow_tree16(__builtin_amdgcn_exp2f(-dtv * LOG2E), pw); \
    float yv0 = 0.f, yv1 = 0.f; \
    _Pragma("unroll") \
    for (int q = 0; q < 4; q++) { \
        float4 Bq = *(const float4*)&sBC[IROW][4 * q]; \
        float4 Cq = *(const float4*)&sBC[IROW][16 + 4 * q]; \
        h[4*q+0] = fmaf(pw[4*q+0], h[4*q+0], dtx * Bq.x); \
        h[4*q+1] = fmaf(pw[4*q+1], h[4*q+1], dtx * Bq.y); \
        h[4*q+2] = fmaf(pw[4*q+2], h[4*q+2], dtx * Bq.z); \
        h[4*q+3] = fmaf(pw[4*q+3], h[4*q+3], dtx * Bq.w); \
        yv0 = fmaf(h[4*q+0], Cq.x, yv0); \
        yv1 = fmaf(h[4*q+1], Cq.y, yv1); \
        yv0 = fmaf(h[4*q+2], Cq.z, yv0); \
        yv1 = fmaf(h[4*q+3], Cq.w, yv1); \
    } \
    float yv = fmaf(xv, Dd, yv0 + yv1); \
    float sg = 1.f / (1.f + __expf(-zv)); \
    yv *= zv * sg; \
    py[YOFF] = f32_to_bf16_rne(yv); }

// ---------------------------------------------------------------------------
// Chunked selective scan, pass 1: per-chunk local scan from h=0.
// LDS-staged B/C slab + 4-deep software prefetch on the dt/xs scalar
// streams (raw slots, convert-on-consume). Last group's refills overshoot
// the chunk by <=4 rows into adjacent workspace buffers (never consumed).
// ---------------------------------------------------------------------------
template<int DIR>
__global__ __launch_bounds__(256, 6) void scan_pass1(
    const ushort_t* __restrict__ xsc, const ushort_t* __restrict__ dtb,
    const float* __restrict__ xdbl, const float* __restrict__ alt,
    const int* __restrict__ flag,
    ushort_t* __restrict__ hstate, float* __restrict__ sumdt_buf)
{
    int g = blockIdx.x % 3;
    int c = (blockIdx.x / 3) % NCHUNK;
    int b = blockIdx.x / (3 * NCHUNK);
    int d = g * 256 + threadIdx.x;
    int tid = threadIdx.x;

    const int l0 = DIR ? (SEQ - 1 - c * LCHUNK) : (c * LCHUNK);
    constexpr ptrdiff_t sN = DIR ? -(ptrdiff_t)D_INNER : (ptrdiff_t)D_INNER;
    size_t row0 = (size_t)b * SEQ + l0;

    // stage this chunk's B/C slab (32 rows x 32 f32 = 4 KB), shared by all d
    __shared__ float sBC[LCHUNK][32];
    {
        int i  = tid >> 3;
        int cc = (tid & 7) * 4;
        size_t rg = row0 + (DIR ? -(ptrdiff_t)i : (ptrdiff_t)i);
        *(float4*)&sBC[i][cc] =
            *(const float4*)(xdbl + rg * XDBL_LD + DT_RANK + cc);
    }
    __syncthreads();

    float h[D_STATE] = {};
    float sdt = 0.f;
    const ushort_t* pdt = dtb + row0 * D_INNER + d;
    const ushort_t* pxs = xsc + row0 * D_INNER + d;

    if (flag[0]) {
        ushort_t d0 = pdt[0], d1 = pdt[sN], d2 = pdt[2*sN], d3 = pdt[3*sN];
        ushort_t x0 = pxs[0], x1 = pxs[sN], x2 = pxs[2*sN], x3 = pxs[3*sN];
        #pragma unroll 1
        for (int t = 0; t < 8; t++) {
            int i0 = t * 4;
            P1_BODY(i0 + 0, d0, x0);
            d0 = pdt[4*sN]; x0 = pxs[4*sN];
            P1_BODY(i0 + 1, d1, x1);
            d1 = pdt[5*sN]; x1 = pxs[5*sN];
            P1_BODY(i0 + 2, d2, x2);
            d2 = pdt[6*sN]; x2 = pxs[6*sN];
            P1_BODY(i0 + 3, d3, x3);
            d3 = pdt[7*sN]; x3 = pxs[7*sN];
            pdt += 4*sN; pxs += 4*sN;
        }
    } else {
        for (int i = 0; i < LCHUNK; i++) {
            float dtv = bf16_to_f32(*pdt);
            float xv  = bf16_to_f32(*pxs);
            float dtx = dtv * xv;
            sdt += dtv;
            #pragma unroll
            for (int q = 0; q < 4; q++) {
                float4 Bq = *(const float4*)&sBC[i][4 * q];
                SLOW_H(4*q+0, Bq.x); SLOW_H(4*q+1, Bq.y);
                SLOW_H(4*q+2, Bq.z); SLOW_H(4*q+3, Bq.w);
            }
            pdt += sN; pxs += sN;
        }
    }
    size_t cidx = (size_t)(b * NCHUNK + c) * D_INNER + d;
    sumdt_buf[cidx] = sdt;
    u16x8 hv0, hv1;
    #pragma unroll
    for (int n = 0; n < 8; n++) { hv0[n] = f32_to_bf16_rne(h[n]);
                                  hv1[n] = f32_to_bf16_rne(h[8 + n]); }
    *(u16x8*)(hstate + cidx * D_STATE)     = hv0;
    *(u16x8*)(hstate + cidx * D_STATE + 8) = hv1;
}

// ---------------------------------------------------------------------------
// Pass 2: in-place combine (carry in f32); hstate[c] -> ENTRY state of c.
// ---------------------------------------------------------------------------
__global__ __launch_bounds__(256) void scan_pass2(
    ushort_t* __restrict__ hstate, const float* __restrict__ sumdt_buf,
    const float* __restrict__ alt)
{
    int gid = blockIdx.x * 256 + threadIdx.x;   // BATCH * D_INNER * 16
    int n = gid & 15;
    int d = (gid >> 4) % D_INNER;
    int b = gid / (16 * D_INNER);
    float A2 = -__expf(alt[n * D_INNER + d]) * LOG2E;
    float h = 0.f;
    for (int c = 0; c < NCHUNK; c++) {
        size_t cidx = (size_t)(b * NCHUNK + c) * D_INNER + d;
        float ho = bf16_to_f32(hstate[cidx * D_STATE + n]);
        hstate[cidx * D_STATE + n] = f32_to_bf16_rne(h);
        h = fmaf(__builtin_amdgcn_exp2f(A2 * sumdt_buf[cidx]), h, ho);
    }
}

// ---------------------------------------------------------------------------
// Pass 3: local scan seeded with entry state; LDS-staged B/C; 4-deep
// software prefetch on dt/xs/z; fuses y = h.C + D*x and SiLU(z) gating.
// ---------------------------------------------------------------------------
template<int DIR>
__global__ __launch_bounds__(256, 6) void scan_pass3(
    const ushort_t* __restrict__ xsc, const ushort_t* __restrict__ dtb,
    const ushort_t* __restrict__ xz, const float* __restrict__ xdbl,
    const float* __restrict__ alt, const float* __restrict__ Dp,
    const int* __restrict__ flag, const ushort_t* __restrict__ hstate,
    ushort_t* __restrict__ y)
{
    int g = blockIdx.x % 3;
    int c = (blockIdx.x / 3) % NCHUNK;
    int b = blockIdx.x / (3 * NCHUNK);
    int d = g * 256 + threadIdx.x;
    int tid = threadIdx.x;

    const int l0 = DIR ? (SEQ - 1 - c * LCHUNK) : (c * LCHUNK);
    constexpr ptrdiff_t sN = DIR ? -(ptrdiff_t)D_INNER : (ptrdiff_t)D_INNER;
    constexpr ptrdiff_t sZ = DIR ? -(ptrdiff_t)1536 : (ptrdiff_t)1536;
    size_t row0 = (size_t)b * SEQ + l0;

    __shared__ float sBC[LCHUNK][32];
    {
        int i  = tid >> 3;
        int cc = (tid & 7) * 4;
        size_t rg = row0 + (DIR ? -(ptrdiff_t)i : (ptrdiff_t)i);
        *(float4*)&sBC[i][cc] =
            *(const float4*)(xdbl + rg * XDBL_LD + DT_RANK + cc);
    }
    __syncthreads();

    size_t cidx = (size_t)(b * NCHUNK + c) * D_INNER + d;
    float h[D_STATE];
    {
        u16x8 hv0 = *(const u16x8*)(hstate + cidx * D_STATE);
        u16x8 hv1 = *(const u16x8*)(hstate + cidx * D_STATE + 8);
        #pragma unroll
        for (int n = 0; n < 8; n++) { h[n] = bf16_to_f32(hv0[n]);
                                      h[8 + n] = bf16_to_f32(hv1[n]); }
    }
    float Dd = Dp[d];

    const ushort_t* pdt = dtb + row0 * D_INNER + d;
    const ushort_t* pxs = xsc + row0 * D_INNER + d;
    const ushort_t* pz  = xz  + row0 * 1536 + D_INNER + d;
    ushort_t*       py  = y + row0 * D_INNER + d;

    if (flag[0]) {
        ushort_t d0 = pdt[0], d1 = pdt[sN], d2 = pdt[2*sN], d3 = pdt[3*sN];
        ushort_t x0 = pxs[0], x1 = pxs[sN], x2 = pxs[2*sN], x3 = pxs[3*sN];
        ushort_t z0 = pz[0],  z1 = pz[sZ],  z2 = pz[2*sZ],  z3 = pz[3*sZ];
        #pragma unroll 1
        for (int t = 0; t < 8; t++) {
            int i0 = t * 4;
            P3_BODY(i0 + 0, d0, x0, z0, 0);
            d0 = pdt[4*sN]; x0 = pxs[4*sN]; z0 = pz[4*sZ];
            P3_BODY(i0 + 1, d1, x1, z1, sN);
            d1 = pdt[5*sN]; x1 = pxs[5*sN]; z1 = pz[5*sZ];
            P3_BODY(i0 + 2, d2, x2, z2, 2*sN);
            d2 = pdt[6*sN]; x2 = pxs[6*sN]; z2 = pz[6*sZ];
            P3_BODY(i0 + 3, d3, x3, z3, 3*sN);
            d3 = pdt[7*sN]; x3 = pxs[7*sN]; z3 = pz[7*sZ];
            pdt += 4*sN; pxs += 4*sN; pz += 4*sZ; py += 4*sN;
        }
    } else {
        for (int i = 0; i < LCHUNK; i++) {
            float dtv = bf16_to_f32(*pdt);
            float xv  = bf16_to_f32(*pxs);
            float zv  = bf16_to_f32(*pz);
            float dtx = dtv * xv;
            float yv0 = 0.f, yv1 = 0.f;
            #pragma unroll
            for (int q = 0; q < 4; q++) {
                float4 Bq = *(const float4*)&sBC[i][4 * q];
                float4 Cq = *(const float4*)&sBC[i][16 + 4 * q];
                SLOW_H(4*q+0, Bq.x); SLOW_H(4*q+1, Bq.y);
                SLOW_H(4*q+2, Bq.z); SLOW_H(4*q+3, Bq.w);
                yv0 = fmaf(h[4*q+0], Cq.x, yv0);
                yv1 = fmaf(h[4*q+1], Cq.y, yv1);
                yv0 = fmaf(h[4*q+2], Cq.z, yv0);
                yv1 = fmaf(h[4*q+3], Cq.w, yv1);
            }
            float yv = fmaf(xv, Dd, yv0 + yv1);
            float sg = 1.f / (1.f + __expf(-zv));
            yv *= zv * sg;
            *py = f32_to_bf16_rne(yv);
            pdt += sN; pxs += sN; pz += sZ; py += sN;
        }
    }
}

// ---------------------------------------------------------------------------
extern "C" void kernel_launch(void* const* d_in, const int* in_sizes, int n_in,
                              void* d_out, int out_size, void* d_ws, size_t ws_size,
                              hipStream_t stream)
{
    const float* x       = (const float*)d_in[0];
    const float* norm_w  = (const float*)d_in[1];
    const float* norm_b  = (const float*)d_in[2];
    const float* in_proj = (const float*)d_in[3];
    const float* conv_w  = (const float*)d_in[4];
    const float* conv_b  = (const float*)d_in[5];
    const float* x_proj  = (const float*)d_in[6];
    const float* dt_w    = (const float*)d_in[7];
    const float* dt_b    = (const float*)d_in[8];
    const float* A_log   = (const float*)d_in[9];
    const float* Dp      = (const float*)d_in[10];
    const float* out_proj= (const float*)d_in[11];
    float* out = (float*)d_out;

    float* ws   = (float*)d_ws;
    // lnb (bf16 BL*384) and ybf (bf16 BL*768) share one region.
    float* reg0 = ws;                ws += (size_t)BL * D_INNER / 2;
    ushort_t* lnb = (ushort_t*)reg0;
    ushort_t* ybf = (ushort_t*)reg0;
    ushort_t* xzb  = (ushort_t*)ws;  ws += (size_t)BL * 1536 / 2;
    ushort_t* xscb = (ushort_t*)ws;  ws += (size_t)BL * D_INNER / 2;
    ushort_t* dtb  = (ushort_t*)ws;  ws += (size_t)BL * D_INNER / 2;
    float* xdbl = ws;                ws += (size_t)BL * XDBL_LD;
    float* sumdt  = ws;              ws += (size_t)BATCH * NCHUNK * D_INNER;
    ushort_t* hstate = (ushort_t*)ws; ws += (size_t)BATCH * NCHUNK * D_INNER * D_STATE / 2;
    ushort_t* wbf_in  = (ushort_t*)ws;  ws += (size_t)N_INP / 2;
    ushort_t* wbf_out = (ushort_t*)ws;  ws += (size_t)N_OUTP / 2;
    ushort_t* xp_bf   = (ushort_t*)ws;  ws += (size_t)N_XP / 2;
    float* cwt = ws;                 ws += (size_t)N_CW;
    float* alt = ws;                 ws += (size_t)N_AL;
    float* dwt = ws;                 ws += (size_t)N_DW;
    int* aflags = (int*)ws;          ws += 2;

    // one-shot weight prep + A-structure check
    prep_kernel<<<N_PREP / 256, 256, 0, stream>>>(
        in_proj, out_proj, x_proj, conv_w, A_log, dt_w,
        wbf_in, wbf_out, xp_bf, cwt, alt, dwt);
    check_A_kernel<<<1, 256, 0, stream>>>(A_log, aflags);

    for (int i = 0; i < 2; i++) {
        const float* hinp = (i == 0) ? x : out;
        ln_kernel<<<BL, 384, 0, stream>>>(hinp, norm_w + i * D_MODEL,
                                          norm_b + i * D_MODEL, lnb);
        gemm_mfma_b16<<<dim3(BL / 128, 1536 / 128), 256, 0, stream>>>(
            lnb, wbf_in + (size_t)i * 1536 * D_MODEL, xzb, 1536, D_MODEL);
        conv_silu_kernel<<<(BL * 96) / 256, 256, 0, stream>>>(
            xzb, cwt + (size_t)i * K_CONV * D_INNER, conv_b + i * D_INNER,
            xscb, i);
        xdbl_mfma<<<BL / 128, 256, 0, stream>>>(
            xscb, xp_bf + (size_t)i * 64 * D_INNER, xdbl);
        dt_kernel<<<(BL / 64) * 3, 256, 0, stream>>>(
            xdbl, dwt + (size_t)i * DT_RANK * D_INNER, dt_b + i * D_INNER, dtb);
        if (i == 0) {
            scan_pass1<0><<<BATCH * NCHUNK * 3, 256, 0, stream>>>(
                xscb, dtb, xdbl, alt, aflags, hstate, sumdt);
        } else {
            scan_pass1<1><<<BATCH * NCHUNK * 3, 256, 0, stream>>>(
                xscb, dtb, xdbl, alt + (size_t)D_STATE * D_INNER,
                aflags + 1, hstate, sumdt);
        }
        scan_pass2<<<(BATCH * D_INNER * D_STATE) / 256, 256, 0, stream>>>(
            hstate, sumdt, alt + (size_t)i * D_STATE * D_INNER);
        if (i == 0) {
            scan_pass3<0><<<BATCH * NCHUNK * 3, 256, 0, stream>>>(
                xscb, dtb, xzb, xdbl, alt, Dp, aflags, hstate, ybf);
        } else {
            scan_pass3<1><<<BATCH * NCHUNK * 3, 256, 0, stream>>>(
                xscb, dtb, xzb, xdbl, alt + (size_t)D_STATE * D_INNER,
                Dp + D_INNER, aflags + 1, hstate, ybf);
        }
        gemm_mfma_f32<<<dim3(BL / 128, D_MODEL / 128), 256, 0, stream>>>(
            ybf, wbf_out + (size_t)i * D_MODEL * D_INNER, hinp, out,
            D_MODEL, D_INNER);
    }
}

// Round 9
// 482.583 us; speedup vs baseline: 1.1304x; 1.1304x over previous
//
#include <hip/hip_runtime.h>
#include <hip/hip_bf16.h>
#include <cstddef>

#define D_MODEL 384
#define D_INNER 768
#define D_STATE 16
#define DT_RANK 24
#define K_CONV  4
#define BATCH   8
#define SEQ     2048
#define BL      (BATCH * SEQ)     // 16384 rows
#define NCHUNK  64
#define LCHUNK  (SEQ / NCHUNK)    // 32
#define XDBL_LD 64                // padded leading dim of x_dbl buffer
#define LOG2E   1.44269504088896f

typedef unsigned short ushort_t;
typedef __bf16 bf16x8 __attribute__((ext_vector_type(8)));
typedef float  f32x4  __attribute__((ext_vector_type(4)));
typedef unsigned short u16x8 __attribute__((ext_vector_type(8)));

#define GLOBAL_AS(p) ((const __attribute__((address_space(1))) void*)(p))
#define LDS_AS(p)    ((__attribute__((address_space(3))) void*)(p))

__device__ __forceinline__ ushort_t f32_to_bf16_rne(float v) {
    unsigned int u = __float_as_uint(v);
    return (ushort_t)((u + 0x7FFFu + ((u >> 16) & 1u)) >> 16);
}
__device__ __forceinline__ float bf16_to_f32(ushort_t u) {
    return __uint_as_float(((unsigned int)u) << 16);
}

// Build w^1..w^16 with a depth-4 product tree (breaks the serial pw chain).
__device__ __forceinline__ void pow_tree16(float w1, float* pw) {
    float w2 = w1 * w1, w4 = w2 * w2, w8 = w4 * w4;
    pw[0] = w1;        pw[1] = w2;        pw[2] = w2 * w1;   pw[3] = w4;
    pw[4] = w4 * w1;   pw[5] = w4 * w2;   pw[6] = w4 * pw[2]; pw[7] = w8;
    pw[8] = w8 * w1;   pw[9] = w8 * w2;   pw[10] = w8 * pw[2]; pw[11] = w8 * w4;
    pw[12] = w8 * pw[4]; pw[13] = w8 * pw[5]; pw[14] = w8 * pw[6]; pw[15] = w8 * w8;
}

// ---------------------------------------------------------------------------
// Merged one-shot weight prep (casts + transposes), both directions.
// ---------------------------------------------------------------------------
#define N_INP  (2 * 1536 * D_MODEL)        // 1179648
#define N_OUTP (2 * D_MODEL * D_INNER)     // 589824
#define N_XP   (2 * 64 * D_INNER)          // 98304
#define N_CW   (2 * K_CONV * D_INNER)      // 6144
#define N_AL   (2 * D_STATE * D_INNER)     // 24576
#define N_DW   (2 * DT_RANK * D_INNER)     // 36864
#define N_PREP (N_INP + N_OUTP + N_XP + N_CW + N_AL + N_DW)

__global__ __launch_bounds__(256) void prep_kernel(
    const float* __restrict__ in_proj, const float* __restrict__ out_proj,
    const float* __restrict__ x_proj, const float* __restrict__ conv_w,
    const float* __restrict__ A_log, const float* __restrict__ dt_w,
    ushort_t* __restrict__ wbf_in, ushort_t* __restrict__ wbf_out,
    ushort_t* __restrict__ xp_bf, float* __restrict__ cwt,
    float* __restrict__ alt, float* __restrict__ dwt)
{
    int i = blockIdx.x * 256 + threadIdx.x;
    if (i < N_INP) {
        wbf_in[i] = f32_to_bf16_rne(in_proj[i]);
        return;
    }
    i -= N_INP;
    if (i < N_OUTP) {
        wbf_out[i] = f32_to_bf16_rne(out_proj[i]);
        return;
    }
    i -= N_OUTP;
    if (i < N_XP) {
        int c   = i % D_INNER;
        int r   = (i / D_INNER) % 64;
        int dir = i / (64 * D_INNER);
        xp_bf[i] = (r < 56)
            ? f32_to_bf16_rne(x_proj[((size_t)dir * 56 + r) * D_INNER + c])
            : (ushort_t)0;
        return;
    }
    i -= N_XP;
    if (i < N_CW) {
        int c = i % D_INNER, k = (i / D_INNER) % K_CONV, dir = i / (K_CONV * D_INNER);
        cwt[i] = conv_w[((size_t)dir * D_INNER + c) * K_CONV + k];
        return;
    }
    i -= N_CW;
    if (i < N_AL) {
        int d = i % D_INNER, n = (i / D_INNER) % D_STATE, dir = i / (D_STATE * D_INNER);
        alt[i] = A_log[((size_t)dir * D_INNER + d) * D_STATE + n];
        return;
    }
    i -= N_AL;
    if (i < N_DW) {
        int d = i % D_INNER, r = (i / D_INNER) % DT_RANK, dir = i / (DT_RANK * D_INNER);
        dwt[i] = dt_w[((size_t)dir * D_INNER + d) * DT_RANK + r];
    }
}

// ---------------------------------------------------------------------------
// Detect the structured-A fast path: exp(A_log[d][n]) == n+1 (per direction).
// ---------------------------------------------------------------------------
__global__ __launch_bounds__(256) void check_A_kernel(
    const float* __restrict__ A_log, int* __restrict__ flags)
{
    __shared__ int ok[2];
    int tid = threadIdx.x;
    if (tid < 2) ok[tid] = 1;
    __syncthreads();
    for (int dir = 0; dir < 2; dir++) {
        bool good = true;
        for (int j = tid; j < D_INNER * D_STATE; j += 256) {
            int n = j % D_STATE;
            float v = __expf(A_log[(size_t)dir * D_INNER * D_STATE + j]);
            good = good && (fabsf(v - (float)(n + 1)) <= 1e-4f * (float)(n + 1));
        }
        if (!good) atomicAnd(&ok[dir], 0);
    }
    __syncthreads();
    if (tid < 2) flags[tid] = ok[tid];
}

// ---------------------------------------------------------------------------
// LayerNorm over last dim (384), output bf16. One block per row, 384 thr.
// ---------------------------------------------------------------------------
__global__ __launch_bounds__(384) void ln_kernel(
    const float* __restrict__ in, const float* __restrict__ w,
    const float* __restrict__ b, ushort_t* __restrict__ out)
{
    int row = blockIdx.x;
    int tid = threadIdx.x;
    float v = in[(size_t)row * D_MODEL + tid];
    float s = v, sq = v * v;
    #pragma unroll
    for (int o = 32; o; o >>= 1) {
        s  += __shfl_down(s, o);
        sq += __shfl_down(sq, o);
    }
    __shared__ float ss[6], ssq[6];
    __shared__ float mb[2];
    int wid = tid >> 6;
    if ((tid & 63) == 0) { ss[wid] = s; ssq[wid] = sq; }
    __syncthreads();
    if (tid == 0) {
        float S = 0.f, Q = 0.f;
        #pragma unroll
        for (int k = 0; k < 6; k++) { S += ss[k]; Q += ssq[k]; }
        float mu  = S * (1.0f / D_MODEL);
        float var = Q * (1.0f / D_MODEL) - mu * mu;
        mb[0] = mu;
        mb[1] = rsqrtf(var + 1e-5f);
    }
    __syncthreads();
    float r = (v - mb[0]) * mb[1] * w[tid] + b[tid];
    out[(size_t)row * D_MODEL + tid] = f32_to_bf16_rne(r);
}

// ---------------------------------------------------------------------------
// bf16 MFMA GEMM, bf16 output. 128x128 tile, BK=32, XOR-swizzled LDS.
// ---------------------------------------------------------------------------
__global__ __launch_bounds__(256) void gemm_mfma_b16(
    const ushort_t* __restrict__ A, const ushort_t* __restrict__ W,
    ushort_t* __restrict__ C, int N, int K)
{
    __shared__ __bf16 As[128 * 32];
    __shared__ __bf16 Ws[128 * 32];
    int tid  = threadIdx.x;
    int bm = blockIdx.x, bn = blockIdx.y;
    int lane = tid & 63, wave = tid >> 6;
    int wr = wave >> 1, wc = wave & 1;
    int quad = lane >> 4, l16 = lane & 15;
    int ca = ((quad ^ ((l16 >> 1) & 3))) * 8;          // read col (swizzled)
    int cbg = ((tid & 3) ^ ((tid >> 3) & 3)) * 8;      // staging col (swizzled)

    const ushort_t* Ag = A + (size_t)(bm * 128 + (tid >> 2)) * K + cbg;
    const ushort_t* Wg = W + (size_t)(bn * 128 + (tid >> 2)) * K + cbg;

    f32x4 acc[4][4] = {};

    for (int k0 = 0; k0 < K; k0 += 32) {
        __syncthreads();
        __builtin_amdgcn_global_load_lds(GLOBAL_AS(Ag + k0),
                                         LDS_AS(As + tid * 8), 16, 0, 0);
        __builtin_amdgcn_global_load_lds(GLOBAL_AS(Ag + (size_t)64 * K + k0),
                                         LDS_AS(As + 2048 + tid * 8), 16, 0, 0);
        __builtin_amdgcn_global_load_lds(GLOBAL_AS(Wg + k0),
                                         LDS_AS(Ws + tid * 8), 16, 0, 0);
        __builtin_amdgcn_global_load_lds(GLOBAL_AS(Wg + (size_t)64 * K + k0),
                                         LDS_AS(Ws + 2048 + tid * 8), 16, 0, 0);
        __syncthreads();

        bf16x8 af[4], wf[4];
        #pragma unroll
        for (int i = 0; i < 4; i++)
            af[i] = *(const bf16x8*)(As + (wr * 64 + i * 16 + l16) * 32 + ca);
        #pragma unroll
        for (int j = 0; j < 4; j++)
            wf[j] = *(const bf16x8*)(Ws + (wc * 64 + j * 16 + l16) * 32 + ca);
        #pragma unroll
        for (int i = 0; i < 4; i++)
            #pragma unroll
            for (int j = 0; j < 4; j++)
                acc[i][j] = __builtin_amdgcn_mfma_f32_16x16x32_bf16(
                    af[i], wf[j], acc[i][j], 0, 0, 0);
    }

    #pragma unroll
    for (int i = 0; i < 4; i++) {
        #pragma unroll
        for (int r = 0; r < 4; r++) {
            int row = bm * 128 + wr * 64 + i * 16 + quad * 4 + r;
            #pragma unroll
            for (int j = 0; j < 4; j++) {
                int col = bn * 128 + wc * 64 + j * 16 + l16;
                C[(size_t)row * N + col] = f32_to_bf16_rne(acc[i][j][r]);
            }
        }
    }
}

// ---------------------------------------------------------------------------
// bf16 MFMA GEMM, f32 output + f32 residual (out_proj). BK=32, swizzled.
// ---------------------------------------------------------------------------
__global__ __launch_bounds__(256) void gemm_mfma_f32(
    const ushort_t* __restrict__ A, const ushort_t* __restrict__ W,
    const float* __restrict__ resid, float* __restrict__ C, int N, int K)
{
    __shared__ __bf16 As[128 * 32];
    __shared__ __bf16 Ws[128 * 32];
    int tid  = threadIdx.x;
    int bm = blockIdx.x, bn = blockIdx.y;
    int lane = tid & 63, wave = tid >> 6;
    int wr = wave >> 1, wc = wave & 1;
    int quad = lane >> 4, l16 = lane & 15;
    int ca = ((quad ^ ((l16 >> 1) & 3))) * 8;
    int cbg = ((tid & 3) ^ ((tid >> 3) & 3)) * 8;

    const ushort_t* Ag = A + (size_t)(bm * 128 + (tid >> 2)) * K + cbg;
    const ushort_t* Wg = W + (size_t)(bn * 128 + (tid >> 2)) * K + cbg;

    f32x4 acc[4][4] = {};

    for (int k0 = 0; k0 < K; k0 += 32) {
        __syncthreads();
        __builtin_amdgcn_global_load_lds(GLOBAL_AS(Ag + k0),
                                         LDS_AS(As + tid * 8), 16, 0, 0);
        __builtin_amdgcn_global_load_lds(GLOBAL_AS(Ag + (size_t)64 * K + k0),
                                         LDS_AS(As + 2048 + tid * 8), 16, 0, 0);
        __builtin_amdgcn_global_load_lds(GLOBAL_AS(Wg + k0),
                                         LDS_AS(Ws + tid * 8), 16, 0, 0);
        __builtin_amdgcn_global_load_lds(GLOBAL_AS(Wg + (size_t)64 * K + k0),
                                         LDS_AS(Ws + 2048 + tid * 8), 16, 0, 0);
        __syncthreads();

        bf16x8 af[4], wf[4];
        #pragma unroll
        for (int i = 0; i < 4; i++)
            af[i] = *(const bf16x8*)(As + (wr * 64 + i * 16 + l16) * 32 + ca);
        #pragma unroll
        for (int j = 0; j < 4; j++)
            wf[j] = *(const bf16x8*)(Ws + (wc * 64 + j * 16 + l16) * 32 + ca);
        #pragma unroll
        for (int i = 0; i < 4; i++)
            #pragma unroll
            for (int j = 0; j < 4; j++)
                acc[i][j] = __builtin_amdgcn_mfma_f32_16x16x32_bf16(
                    af[i], wf[j], acc[i][j], 0, 0, 0);
    }

    #pragma unroll
    for (int i = 0; i < 4; i++) {
        #pragma unroll
        for (int r = 0; r < 4; r++) {
            int row = bm * 128 + wr * 64 + i * 16 + quad * 4 + r;
            #pragma unroll
            for (int j = 0; j < 4; j++) {
                int col = bn * 128 + wc * 64 + j * 16 + l16;
                size_t idx = (size_t)row * N + col;
                C[idx] = acc[i][j][r] + resid[idx];
            }
        }
    }
}

// ---------------------------------------------------------------------------
// x_dbl = xs(bf16) @ x_proj^T(bf16, 64x768 zero-padded), f32 out (BLx64).
// BK=32, swizzled LDS like the big GEMMs.
// ---------------------------------------------------------------------------
__global__ __launch_bounds__(256) void xdbl_mfma(
    const ushort_t* __restrict__ A, const ushort_t* __restrict__ W,
    float* __restrict__ C)
{
    __shared__ __bf16 As[128 * 32];
    __shared__ __bf16 Ws[64 * 32];
    int tid  = threadIdx.x;
    int bm = blockIdx.x;
    int lane = tid & 63, wave = tid >> 6;
    int quad = lane >> 4, l16 = lane & 15;
    int ca = ((quad ^ ((l16 >> 1) & 3))) * 8;
    int cbg = ((tid & 3) ^ ((tid >> 3) & 3)) * 8;

    const ushort_t* Ag = A + (size_t)(bm * 128 + (tid >> 2)) * D_INNER + cbg;
    const ushort_t* Wg = W + (size_t)(tid >> 2) * D_INNER + cbg;

    f32x4 acc[2][4] = {};

    for (int k0 = 0; k0 < D_INNER; k0 += 32) {
        __syncthreads();
        __builtin_amdgcn_global_load_lds(GLOBAL_AS(Ag + k0),
                                         LDS_AS(As + tid * 8), 16, 0, 0);
        __builtin_amdgcn_global_load_lds(GLOBAL_AS(Ag + (size_t)64 * D_INNER + k0),
                                         LDS_AS(As + 2048 + tid * 8), 16, 0, 0);
        __builtin_amdgcn_global_load_lds(GLOBAL_AS(Wg + k0),
                                         LDS_AS(Ws + tid * 8), 16, 0, 0);
        __syncthreads();

        bf16x8 af[2], wf[4];
        #pragma unroll
        for (int i = 0; i < 2; i++)
            af[i] = *(const bf16x8*)(As + (wave * 32 + i * 16 + l16) * 32 + ca);
        #pragma unroll
        for (int j = 0; j < 4; j++)
            wf[j] = *(const bf16x8*)(Ws + (j * 16 + l16) * 32 + ca);
        #pragma unroll
        for (int i = 0; i < 2; i++)
            #pragma unroll
            for (int j = 0; j < 4; j++)
                acc[i][j] = __builtin_amdgcn_mfma_f32_16x16x32_bf16(
                    af[i], wf[j], acc[i][j], 0, 0, 0);
    }

    #pragma unroll
    for (int i = 0; i < 2; i++) {
        #pragma unroll
        for (int r = 0; r < 4; r++) {
            int row = bm * 128 + wave * 32 + i * 16 + quad * 4 + r;
            #pragma unroll
            for (int j = 0; j < 4; j++) {
                int col = j * 16 + l16;
                C[(size_t)row * XDBL_LD + col] = acc[i][j][r];
            }
        }
    }
}

// ---------------------------------------------------------------------------
// dt = softplus(xdbl[:,0:24] @ dwt + bias), bf16 out, ROW-MAJOR [row][d].
// 64 rows per block; scalar stores are coalesced across the 768 d lanes.
// ---------------------------------------------------------------------------
__global__ __launch_bounds__(256) void dt_kernel(
    const float* __restrict__ xdbl, const float* __restrict__ dwt,
    const float* __restrict__ dtbias, ushort_t* __restrict__ dtb)
{
    int g    = blockIdx.x % 3;
    int row0 = (blockIdx.x / 3) * 64;
    int tid  = threadIdx.x;
    int d    = g * 256 + tid;
    float w[DT_RANK];
    #pragma unroll
    for (int r = 0; r < DT_RANK; r++) w[r] = dwt[r * D_INNER + d];
    float bias = dtbias[d];
    __shared__ float xd[64][DT_RANK];
    for (int idx = tid; idx < 64 * DT_RANK; idx += 256) {
        int rr = idx / DT_RANK, cc = idx % DT_RANK;
        xd[rr][cc] = xdbl[(size_t)(row0 + rr) * XDBL_LD + cc];
    }
    __syncthreads();
    #pragma unroll 4
    for (int i = 0; i < 64; i++) {
        float acc = bias;
        #pragma unroll
        for (int r = 0; r < DT_RANK; r++) acc = fmaf(xd[i][r], w[r], acc);
        float sp = acc > 20.f ? acc : __logf(1.f + __expf(acc));
        dtb[(size_t)(row0 + i) * D_INNER + d] = f32_to_bf16_rne(sp);
    }
}

// ---------------------------------------------------------------------------
// Causal depthwise conv (k=4) + bias + SiLU, bf16 in/out, 8 ch per thread.
// ---------------------------------------------------------------------------
__global__ __launch_bounds__(256) void conv_silu_kernel(
    const ushort_t* __restrict__ xz, const float* __restrict__ cwt,
    const float* __restrict__ cb, ushort_t* __restrict__ xsc, int dir)
{
    int idx8 = blockIdx.x * 256 + threadIdx.x;   // BL * 96
    int c8   = (idx8 % 96) * 8;
    int row  = idx8 / 96;
    int l    = row % SEQ;
    int b0   = row - l;

    float acc[8];
    float4 bv0 = *(const float4*)(cb + c8);
    float4 bv1 = *(const float4*)(cb + c8 + 4);
    acc[0] = bv0.x; acc[1] = bv0.y; acc[2] = bv0.z; acc[3] = bv0.w;
    acc[4] = bv1.x; acc[5] = bv1.y; acc[6] = bv1.z; acc[7] = bv1.w;

    #pragma unroll
    for (int k = 0; k < 4; k++) {
        int ls = dir ? (l + k) : (l - 3 + k);
        int wk = dir ? (3 - k) : k;
        bool ok = dir ? (ls < SEQ) : (ls >= 0);
        if (ok) {
            u16x8 v = *(const u16x8*)(xz + (size_t)(b0 + ls) * 1536 + c8);
            float4 w0 = *(const float4*)(cwt + wk * D_INNER + c8);
            float4 w1 = *(const float4*)(cwt + wk * D_INNER + c8 + 4);
            float wv[8] = {w0.x, w0.y, w0.z, w0.w, w1.x, w1.y, w1.z, w1.w};
            #pragma unroll
            for (int j = 0; j < 8; j++)
                acc[j] = fmaf(bf16_to_f32(v[j]), wv[j], acc[j]);
        }
    }
    u16x8 o;
    #pragma unroll
    for (int j = 0; j < 8; j++) {
        float sg = 1.0f / (1.0f + __expf(-acc[j]));
        o[j] = f32_to_bf16_rne(acc[j] * sg);
    }
    *(u16x8*)(xsc + (size_t)row * D_INNER + c8) = o;
}

// h-update helper for the structured-A slow path (volatile alt read defeats
// LICM so the never-taken branch can't inflate the fast path's VGPR count).
#define SLOW_H(idx, bq) { \
    float a_ = *(const volatile float*)(alt + (idx) * D_INNER + d); \
    float e_ = __builtin_amdgcn_exp2f(dtv * (-__expf(a_) * LOG2E)); \
    h[idx] = fmaf(e_, h[idx], dtx * (bq)); }

// Fast-path step bodies. Raw bf16 slot values are converted at CONSUME time
// so the prefetched loads' s_waitcnt lands 4 steps after issue.
#define P1_BODY(IROW, DRAW, XRAW) { \
    float dtv = bf16_to_f32(DRAW); \
    float xv  = bf16_to_f32(XRAW); \
    float dtx = dtv * xv; \
    sdt += dtv; \
    float pw[D_STATE]; \
    pow_tree16(__builtin_amdgcn_exp2f(-dtv * LOG2E), pw); \
    _Pragma("unroll") \
    for (int q = 0; q < 4; q++) { \
        float4 Bq = *(const float4*)&sBC[IROW][4 * q]; \
        h[4*q+0] = fmaf(pw[4*q+0], h[4*q+0], dtx * Bq.x); \
        h[4*q+1] = fmaf(pw[4*q+1], h[4*q+1], dtx * Bq.y); \
        h[4*q+2] = fmaf(pw[4*q+2], h[4*q+2], dtx * Bq.z); \
        h[4*q+3] = fmaf(pw[4*q+3], h[4*q+3], dtx * Bq.w); \
    } }

#define P3_BODY(IROW, DRAW, XRAW, ZRAW, YOFF) { \
    float dtv = bf16_to_f32(DRAW); \
    float xv  = bf16_to_f32(XRAW); \
    float zv  = bf16_to_f32(ZRAW); \
    float dtx = dtv * xv; \
    float pw[D_STATE]; \
    pow_tree16(__builtin_amdgcn_exp2f(-dtv * LOG2E), pw); \
    float yv0 = 0.f, yv1 = 0.f; \
    _Pragma("unroll") \
    for (int q = 0; q < 4; q++) { \
        float4 Bq = *(const float4*)&sBC[IROW][4 * q]; \
        float4 Cq = *(const float4*)&sBC[IROW][16 + 4 * q]; \
        h[4*q+0] = fmaf(pw[4*q+0], h[4*q+0], dtx * Bq.x); \
        h[4*q+1] = fmaf(pw[4*q+1], h[4*q+1], dtx * Bq.y); \
        h[4*q+2] = fmaf(pw[4*q+2], h[4*q+2], dtx * Bq.z); \
        h[4*q+3] = fmaf(pw[4*q+3], h[4*q+3], dtx * Bq.w); \
        yv0 = fmaf(h[4*q+0], Cq.x, yv0); \
        yv1 = fmaf(h[4*q+1], Cq.y, yv1); \
        yv0 = fmaf(h[4*q+2], Cq.z, yv0); \
        yv1 = fmaf(h[4*q+3], Cq.w, yv1); \
    } \
    float yv = fmaf(xv, Dd, yv0 + yv1); \
    float sg = 1.f / (1.f + __expf(-zv)); \
    yv *= zv * sg; \
    py[YOFF] = f32_to_bf16_rne(yv); }

// ---------------------------------------------------------------------------
// Chunked selective scan, pass 1: per-chunk local scan from h=0.
// LDS-staged B/C slab + 4-deep software prefetch on the dt/xs scalar
// streams (raw slots, convert-on-consume). No forced occupancy bound:
// r8 showed __launch_bounds__(256,6) makes the compiler spill the slots
// to scratch (WRITE_SIZE 24->170 MB). Overshoot reads (<=4 rows past the
// chunk) land in adjacent workspace buffers, never consumed.
// ---------------------------------------------------------------------------
template<int DIR>
__global__ __launch_bounds__(256) void scan_pass1(
    const ushort_t* __restrict__ xsc, const ushort_t* __restrict__ dtb,
    const float* __restrict__ xdbl, const float* __restrict__ alt,
    const int* __restrict__ flag,
    ushort_t* __restrict__ hstate, float* __restrict__ sumdt_buf)
{
    int g = blockIdx.x % 3;
    int c = (blockIdx.x / 3) % NCHUNK;
    int b = blockIdx.x / (3 * NCHUNK);
    int d = g * 256 + threadIdx.x;
    int tid = threadIdx.x;

    const int l0 = DIR ? (SEQ - 1 - c * LCHUNK) : (c * LCHUNK);
    constexpr ptrdiff_t sN = DIR ? -(ptrdiff_t)D_INNER : (ptrdiff_t)D_INNER;
    size_t row0 = (size_t)b * SEQ + l0;

    // stage this chunk's B/C slab (32 rows x 32 f32 = 4 KB), shared by all d
    __shared__ float sBC[LCHUNK][32];
    {
        int i  = tid >> 3;
        int cc = (tid & 7) * 4;
        size_t rg = row0 + (DIR ? -(ptrdiff_t)i : (ptrdiff_t)i);
        *(float4*)&sBC[i][cc] =
            *(const float4*)(xdbl + rg * XDBL_LD + DT_RANK + cc);
    }
    __syncthreads();

    float h[D_STATE] = {};
    float sdt = 0.f;
    const ushort_t* pdt = dtb + row0 * D_INNER + d;
    const ushort_t* pxs = xsc + row0 * D_INNER + d;

    if (flag[0]) {
        ushort_t d0 = pdt[0], d1 = pdt[sN], d2 = pdt[2*sN], d3 = pdt[3*sN];
        ushort_t x0 = pxs[0], x1 = pxs[sN], x2 = pxs[2*sN], x3 = pxs[3*sN];
        #pragma unroll 1
        for (int t = 0; t < 8; t++) {
            int i0 = t * 4;
            P1_BODY(i0 + 0, d0, x0);
            d0 = pdt[4*sN]; x0 = pxs[4*sN];
            P1_BODY(i0 + 1, d1, x1);
            d1 = pdt[5*sN]; x1 = pxs[5*sN];
            P1_BODY(i0 + 2, d2, x2);
            d2 = pdt[6*sN]; x2 = pxs[6*sN];
            P1_BODY(i0 + 3, d3, x3);
            d3 = pdt[7*sN]; x3 = pxs[7*sN];
            pdt += 4*sN; pxs += 4*sN;
        }
    } else {
        for (int i = 0; i < LCHUNK; i++) {
            float dtv = bf16_to_f32(*pdt);
            float xv  = bf16_to_f32(*pxs);
            float dtx = dtv * xv;
            sdt += dtv;
            #pragma unroll
            for (int q = 0; q < 4; q++) {
                float4 Bq = *(const float4*)&sBC[i][4 * q];
                SLOW_H(4*q+0, Bq.x); SLOW_H(4*q+1, Bq.y);
                SLOW_H(4*q+2, Bq.z); SLOW_H(4*q+3, Bq.w);
            }
            pdt += sN; pxs += sN;
        }
    }
    size_t cidx = (size_t)(b * NCHUNK + c) * D_INNER + d;
    sumdt_buf[cidx] = sdt;
    u16x8 hv0, hv1;
    #pragma unroll
    for (int n = 0; n < 8; n++) { hv0[n] = f32_to_bf16_rne(h[n]);
                                  hv1[n] = f32_to_bf16_rne(h[8 + n]); }
    *(u16x8*)(hstate + cidx * D_STATE)     = hv0;
    *(u16x8*)(hstate + cidx * D_STATE + 8) = hv1;
}

// ---------------------------------------------------------------------------
// Pass 2: in-place combine (carry in f32); hstate[c] -> ENTRY state of c.
// ---------------------------------------------------------------------------
__global__ __launch_bounds__(256) void scan_pass2(
    ushort_t* __restrict__ hstate, const float* __restrict__ sumdt_buf,
    const float* __restrict__ alt)
{
    int gid = blockIdx.x * 256 + threadIdx.x;   // BATCH * D_INNER * 16
    int n = gid & 15;
    int d = (gid >> 4) % D_INNER;
    int b = gid / (16 * D_INNER);
    float A2 = -__expf(alt[n * D_INNER + d]) * LOG2E;
    float h = 0.f;
    for (int c = 0; c < NCHUNK; c++) {
        size_t cidx = (size_t)(b * NCHUNK + c) * D_INNER + d;
        float ho = bf16_to_f32(hstate[cidx * D_STATE + n]);
        hstate[cidx * D_STATE + n] = f32_to_bf16_rne(h);
        h = fmaf(__builtin_amdgcn_exp2f(A2 * sumdt_buf[cidx]), h, ho);
    }
}

// ---------------------------------------------------------------------------
// Pass 3: local scan seeded with entry state; LDS-staged B/C; 4-deep
// software prefetch on dt/xs/z; fuses y = h.C + D*x and SiLU(z) gating.
// ---------------------------------------------------------------------------
template<int DIR>
__global__ __launch_bounds__(256) void scan_pass3(
    const ushort_t* __restrict__ xsc, const ushort_t* __restrict__ dtb,
    const ushort_t* __restrict__ xz, const float* __restrict__ xdbl,
    const float* __restrict__ alt, const float* __restrict__ Dp,
    const int* __restrict__ flag, const ushort_t* __restrict__ hstate,
    ushort_t* __restrict__ y)
{
    int g = blockIdx.x % 3;
    int c = (blockIdx.x / 3) % NCHUNK;
    int b = blockIdx.x / (3 * NCHUNK);
    int d = g * 256 + threadIdx.x;
    int tid = threadIdx.x;

    const int l0 = DIR ? (SEQ - 1 - c * LCHUNK) : (c * LCHUNK);
    constexpr ptrdiff_t sN = DIR ? -(ptrdiff_t)D_INNER : (ptrdiff_t)D_INNER;
    constexpr ptrdiff_t sZ = DIR ? -(ptrdiff_t)1536 : (ptrdiff_t)1536;
    size_t row0 = (size_t)b * SEQ + l0;

    __shared__ float sBC[LCHUNK][32];
    {
        int i  = tid >> 3;
        int cc = (tid & 7) * 4;
        size_t rg = row0 + (DIR ? -(ptrdiff_t)i : (ptrdiff_t)i);
        *(float4*)&sBC[i][cc] =
            *(const float4*)(xdbl + rg * XDBL_LD + DT_RANK + cc);
    }
    __syncthreads();

    size_t cidx = (size_t)(b * NCHUNK + c) * D_INNER + d;
    float h[D_STATE];
    {
        u16x8 hv0 = *(const u16x8*)(hstate + cidx * D_STATE);
        u16x8 hv1 = *(const u16x8*)(hstate + cidx * D_STATE + 8);
        #pragma unroll
        for (int n = 0; n < 8; n++) { h[n] = bf16_to_f32(hv0[n]);
                                      h[8 + n] = bf16_to_f32(hv1[n]); }
    }
    float Dd = Dp[d];

    const ushort_t* pdt = dtb + row0 * D_INNER + d;
    const ushort_t* pxs = xsc + row0 * D_INNER + d;
    const ushort_t* pz  = xz  + row0 * 1536 + D_INNER + d;
    ushort_t*       py  = y + row0 * D_INNER + d;

    if (flag[0]) {
        ushort_t d0 = pdt[0], d1 = pdt[sN], d2 = pdt[2*sN], d3 = pdt[3*sN];
        ushort_t x0 = pxs[0], x1 = pxs[sN], x2 = pxs[2*sN], x3 = pxs[3*sN];
        ushort_t z0 = pz[0],  z1 = pz[sZ],  z2 = pz[2*sZ],  z3 = pz[3*sZ];
        #pragma unroll 1
        for (int t = 0; t < 8; t++) {
            int i0 = t * 4;
            P3_BODY(i0 + 0, d0, x0, z0, 0);
            d0 = pdt[4*sN]; x0 = pxs[4*sN]; z0 = pz[4*sZ];
            P3_BODY(i0 + 1, d1, x1, z1, sN);
            d1 = pdt[5*sN]; x1 = pxs[5*sN]; z1 = pz[5*sZ];
            P3_BODY(i0 + 2, d2, x2, z2, 2*sN);
            d2 = pdt[6*sN]; x2 = pxs[6*sN]; z2 = pz[6*sZ];
            P3_BODY(i0 + 3, d3, x3, z3, 3*sN);
            d3 = pdt[7*sN]; x3 = pxs[7*sN]; z3 = pz[7*sZ];
            pdt += 4*sN; pxs += 4*sN; pz += 4*sZ; py += 4*sN;
        }
    } else {
        for (int i = 0; i < LCHUNK; i++) {
            float dtv = bf16_to_f32(*pdt);
            float xv  = bf16_to_f32(*pxs);
            float zv  = bf16_to_f32(*pz);
            float dtx = dtv * xv;
            float yv0 = 0.f, yv1 = 0.f;
            #pragma unroll
            for (int q = 0; q < 4; q++) {
                float4 Bq = *(const float4*)&sBC[i][4 * q];
                float4 Cq = *(const float4*)&sBC[i][16 + 4 * q];
                SLOW_H(4*q+0, Bq.x); SLOW_H(4*q+1, Bq.y);
                SLOW_H(4*q+2, Bq.z); SLOW_H(4*q+3, Bq.w);
                yv0 = fmaf(h[4*q+0], Cq.x, yv0);
                yv1 = fmaf(h[4*q+1], Cq.y, yv1);
                yv0 = fmaf(h[4*q+2], Cq.z, yv0);
                yv1 = fmaf(h[4*q+3], Cq.w, yv1);
            }
            float yv = fmaf(xv, Dd, yv0 + yv1);
            float sg = 1.f / (1.f + __expf(-zv));
            yv *= zv * sg;
            *py = f32_to_bf16_rne(yv);
            pdt += sN; pxs += sN; pz += sZ; py += sN;
        }
    }
}

// ---------------------------------------------------------------------------
extern "C" void kernel_launch(void* const* d_in, const int* in_sizes, int n_in,
                              void* d_out, int out_size, void* d_ws, size_t ws_size,
                              hipStream_t stream)
{
    const float* x       = (const float*)d_in[0];
    const float* norm_w  = (const float*)d_in[1];
    const float* norm_b  = (const float*)d_in[2];
    const float* in_proj = (const float*)d_in[3];
    const float* conv_w  = (const float*)d_in[4];
    const float* conv_b  = (const float*)d_in[5];
    const float* x_proj  = (const float*)d_in[6];
    const float* dt_w    = (const float*)d_in[7];
    const float* dt_b    = (const float*)d_in[8];
    const float* A_log   = (const float*)d_in[9];
    const float* Dp      = (const float*)d_in[10];
    const float* out_proj= (const float*)d_in[11];
    float* out = (float*)d_out;

    float* ws   = (float*)d_ws;
    // lnb (bf16 BL*384) and ybf (bf16 BL*768) share one region.
    float* reg0 = ws;                ws += (size_t)BL * D_INNER / 2;
    ushort_t* lnb = (ushort_t*)reg0;
    ushort_t* ybf = (ushort_t*)reg0;
    ushort_t* xzb  = (ushort_t*)ws;  ws += (size_t)BL * 1536 / 2;
    ushort_t* xscb = (ushort_t*)ws;  ws += (size_t)BL * D_INNER / 2;
    ushort_t* dtb  = (ushort_t*)ws;  ws += (size_t)BL * D_INNER / 2;
    float* xdbl = ws;                ws += (size_t)BL * XDBL_LD;
    float* sumdt  = ws;              ws += (size_t)BATCH * NCHUNK * D_INNER;
    ushort_t* hstate = (ushort_t*)ws; ws += (size_t)BATCH * NCHUNK * D_INNER * D_STATE / 2;
    ushort_t* wbf_in  = (ushort_t*)ws;  ws += (size_t)N_INP / 2;
    ushort_t* wbf_out = (ushort_t*)ws;  ws += (size_t)N_OUTP / 2;
    ushort_t* xp_bf   = (ushort_t*)ws;  ws += (size_t)N_XP / 2;
    float* cwt = ws;                 ws += (size_t)N_CW;
    float* alt = ws;                 ws += (size_t)N_AL;
    float* dwt = ws;                 ws += (size_t)N_DW;
    int* aflags = (int*)ws;          ws += 2;

    // one-shot weight prep + A-structure check
    prep_kernel<<<N_PREP / 256, 256, 0, stream>>>(
        in_proj, out_proj, x_proj, conv_w, A_log, dt_w,
        wbf_in, wbf_out, xp_bf, cwt, alt, dwt);
    check_A_kernel<<<1, 256, 0, stream>>>(A_log, aflags);

    for (int i = 0; i < 2; i++) {
        const float* hinp = (i == 0) ? x : out;
        ln_kernel<<<BL, 384, 0, stream>>>(hinp, norm_w + i * D_MODEL,
                                          norm_b + i * D_MODEL, lnb);
        gemm_mfma_b16<<<dim3(BL / 128, 1536 / 128), 256, 0, stream>>>(
            lnb, wbf_in + (size_t)i * 1536 * D_MODEL, xzb, 1536, D_MODEL);
        conv_silu_kernel<<<(BL * 96) / 256, 256, 0, stream>>>(
            xzb, cwt + (size_t)i * K_CONV * D_INNER, conv_b + i * D_INNER,
            xscb, i);
        xdbl_mfma<<<BL / 128, 256, 0, stream>>>(
            xscb, xp_bf + (size_t)i * 64 * D_INNER, xdbl);
        dt_kernel<<<(BL / 64) * 3, 256, 0, stream>>>(
            xdbl, dwt + (size_t)i * DT_RANK * D_INNER, dt_b + i * D_INNER, dtb);
        if (i == 0) {
            scan_pass1<0><<<BATCH * NCHUNK * 3, 256, 0, stream>>>(
                xscb, dtb, xdbl, alt, aflags, hstate, sumdt);
        } else {
            scan_pass1<1><<<BATCH * NCHUNK * 3, 256, 0, stream>>>(
                xscb, dtb, xdbl, alt + (size_t)D_STATE * D_INNER,
                aflags + 1, hstate, sumdt);
        }
        scan_pass2<<<(BATCH * D_INNER * D_STATE) / 256, 256, 0, stream>>>(
            hstate, sumdt, alt + (size_t)i * D_STATE * D_INNER);
        if (i == 0) {
            scan_pass3<0><<<BATCH * NCHUNK * 3, 256, 0, stream>>>(
                xscb, dtb, xzb, xdbl, alt, Dp, aflags, hstate, ybf);
        } else {
            scan_pass3<1><<<BATCH * NCHUNK * 3, 256, 0, stream>>>(
                xscb, dtb, xzb, xdbl, alt + (size_t)D_STATE * D_INNER,
                Dp + D_INNER, aflags + 1, hstate, ybf);
        }
        gemm_mfma_f32<<<dim3(BL / 128, D_MODEL / 128), 256, 0, stream>>>(
            ybf, wbf_out + (size_t)i * D_MODEL * D_INNER, hinp, out,
            D_MODEL, D_INNER);
    }
}